// Round 9
// baseline (17.378 us; speedup 1.0000x reference)
//
#include <hip/hip_runtime.h>
#include <hip/hip_bf16.h>

#define Mdim 50
#define Ndim 10000
#define Edim 128
#define NT 200                  // row tiles of 16 (3200/16)
#define XSTR 296                // XL stride in shorts (16B-aligned frags, spread banks)
#define HSTR 264                // HF stride in shorts

using s8v   = __attribute__((ext_vector_type(8))) short;
using f32x4 = __attribute__((ext_vector_type(4))) float;

__device__ __forceinline__ short f2bf(float x) {
    return __builtin_bit_cast(short, __float2bfloat16(x));
}
__device__ __forceinline__ s8v cvt8(float4 a, float4 b) {
    s8v v;
    v[0] = f2bf(a.x); v[1] = f2bf(a.y); v[2] = f2bf(a.z); v[3] = f2bf(a.w);
    v[4] = f2bf(b.x); v[5] = f2bf(b.y); v[6] = f2bf(b.z); v[7] = f2bf(b.w);
    return v;
}
__device__ __forceinline__ s8v ld8g(const float* __restrict__ p) {
    const float4* q = (const float4*)p;
    return cvt8(q[0], q[1]);
}

// Single kernel, 200 blocks x 512 threads (8 waves). Block t: rows 16t..16t+15.
// Wave w owns output n-tile w; its 21 B-fragments are register-resident.
// Fragment convention: lane l=(r16=l&15, h=l>>4) holds row r16, k-cols kt*32+h*8..+7.
// C/D layout: col = lane&15, row = (lane>>4)*4 + reg.
// out = [gvec | h] @ W_a^T + b_a (K=256); gvec = graph_row @ W_g^T + b_g (A direct
// from global, no LDS/barrier dep); h = X @ Wc^T (K=288, bias folded at col 267).
__global__ __launch_bounds__(512) void k_one(
    const float* __restrict__ cities, const float* __restrict__ graph,
    const float* __restrict__ astate,
    const float* __restrict__ W_dp, const float* __restrict__ b_dp,
    const float* __restrict__ W_dc, const float* __restrict__ b_dc,
    const float* __restrict__ W_nc, const float* __restrict__ b_nc,
    const float* __restrict__ W_ps, const float* __restrict__ b_ps,
    const float* __restrict__ W_g,  const float* __restrict__ b_g,
    const float* __restrict__ W_a,  const float* __restrict__ b_a,
    float* __restrict__ out)
{
    const int t = blockIdx.x, tid = threadIdx.x;
    const int w = tid >> 6, l = tid & 63;
    const int r16 = l & 15, h = l >> 4;
    const int o = w * 16 + r16;          // B-row / output channel for this lane
    const int kb = h * 8;                // k-offset within a 32-wide K-tile

    __shared__ __align__(16) short XL[16][XSTR];
    __shared__ __align__(16) short HF[16][HSTR];   // cols 0..127 gvec, 128..255 h

    // ---- issue ALL B-fragment loads early (independent, latency-overlapped) ----
    s8v Bc[9], Ba[8], Bg[4];
    {
        const float* wdp = W_dp + (size_t)o * 256;
        #pragma unroll
        for (int kt = 0; kt < 8; ++kt) Bc[kt] = ld8g(wdp + kt * 32 + kb);
        s8v bf = (s8v)0;                 // kt=8: cols 256..287 = dc(4)|nc(4)|ps(3)|bias
        if (h == 0) {
            bf = cvt8(*(const float4*)(W_dc + o * 4), *(const float4*)(W_nc + o * 4));
        } else if (h == 1) {
            bf[0] = f2bf(W_ps[o * 3]); bf[1] = f2bf(W_ps[o * 3 + 1]); bf[2] = f2bf(W_ps[o * 3 + 2]);
            bf[3] = f2bf(b_dp[o] + b_dc[o] + b_nc[o] + b_ps[o]);
        }
        Bc[8] = bf;
        const float* wa = W_a + (size_t)o * 256;
        #pragma unroll
        for (int kt = 0; kt < 8; ++kt) Ba[kt] = ld8g(wa + kt * 32 + kb);
        const float* wg = W_g + (size_t)o * Edim;
        #pragma unroll
        for (int kt = 0; kt < 4; ++kt) Bg[kt] = ld8g(wg + kt * 32 + kb);
    }
    const float bgv = b_g[o], bav = b_a[o];

    // ---- gather 32 city rows coalesced into XL; indices direct from global ----
    #pragma unroll
    for (int i = 0; i < 2; ++i) {
        const int f = (i * 512 + tid) * 4;     // 0..4092, step 4
        const int r = f >> 8, c = f & 255;
        const int R = t * 16 + r;
        const int b = R / Mdim;
        int ci = (int)astate[(size_t)R * 13 + (c < 128 ? 0 : 1)];
        ci = min(max(ci, 0), Ndim - 1);
        const float4 v = *(const float4*)(cities + ((size_t)b * Ndim + ci) * Edim + (c & 127));
        XL[r][c]     = f2bf(v.x);
        XL[r][c + 1] = f2bf(v.y);
        XL[r][c + 2] = f2bf(v.z);
        XL[r][c + 3] = f2bf(v.w);
    }
    {   // feats cols 256..287: 512 threads = 16 rows x 32 cols, one each
        const int r = tid >> 5, cc = tid & 31;
        float x = 0.f;
        if (cc < 11)       x = astate[(size_t)(t * 16 + r) * 13 + 2 + cc];
        else if (cc == 11) x = 1.0f;
        XL[r][256 + cc] = f2bf(x);
    }

    // ---- GEMM_g (no LDS dep — overlaps gather): gvec -> HF[:, 0:128] ----
    {
        const float* grow = graph + (size_t)((t * 16 + r16) / Mdim) * Edim;
        f32x4 ag = (f32x4)0.f;
        #pragma unroll
        for (int kt = 0; kt < 4; ++kt) {
            const s8v A = ld8g(grow + kt * 32 + kb);
            ag = __builtin_amdgcn_mfma_f32_16x16x32_bf16(A, Bg[kt], ag, 0, 0, 0);
        }
        #pragma unroll
        for (int r = 0; r < 4; ++r) HF[h * 4 + r][o] = f2bf(ag[r] + bgv);
    }
    __syncthreads();

    // ---- GEMM1: h = X @ Wc^T -> HF[:, 128:256] ----
    f32x4 a1 = (f32x4)0.f;
    #pragma unroll
    for (int kt = 0; kt < 9; ++kt) {
        const s8v A = *(const s8v*)&XL[r16][kt * 32 + kb];
        a1 = __builtin_amdgcn_mfma_f32_16x16x32_bf16(A, Bc[kt], a1, 0, 0, 0);
    }
    #pragma unroll
    for (int r = 0; r < 4; ++r) HF[h * 4 + r][Edim + o] = f2bf(a1[r]);
    __syncthreads();

    // ---- GEMM2: out = [gvec|h] @ W_a^T + b_a (K=256) ----
    f32x4 a2 = (f32x4)0.f;
    #pragma unroll
    for (int kt = 0; kt < 8; ++kt) {
        const s8v A = *(const s8v*)&HF[r16][kt * 32 + kb];
        a2 = __builtin_amdgcn_mfma_f32_16x16x32_bf16(A, Ba[kt], a2, 0, 0, 0);
    }
    #pragma unroll
    for (int r = 0; r < 4; ++r) {
        const int R2 = t * 16 + h * 4 + r;
        out[(size_t)R2 * Edim + o] = a2[r] + bav;
    }
}

extern "C" void kernel_launch(void* const* d_in, const int* in_sizes, int n_in,
                              void* d_out, int out_size, void* d_ws, size_t ws_size,
                              hipStream_t stream) {
    const float* cities = (const float*)d_in[0];
    const float* graph  = (const float*)d_in[1];
    const float* astate = (const float*)d_in[2];
    const float* W_dp = (const float*)d_in[3];
    const float* b_dp = (const float*)d_in[4];
    const float* W_dc = (const float*)d_in[5];
    const float* b_dc = (const float*)d_in[6];
    const float* W_nc = (const float*)d_in[7];
    const float* b_nc = (const float*)d_in[8];
    const float* W_ps = (const float*)d_in[9];
    const float* b_ps = (const float*)d_in[10];
    const float* W_g  = (const float*)d_in[11];
    const float* b_g  = (const float*)d_in[12];
    const float* W_a  = (const float*)d_in[13];
    const float* b_a  = (const float*)d_in[14];
    float* out = (float*)d_out;

    hipLaunchKernelGGL(k_one, dim3(NT), dim3(512), 0, stream,
                       cities, graph, astate,
                       W_dp, b_dp, W_dc, b_dc, W_nc, b_nc, W_ps, b_ps,
                       W_g, b_g, W_a, b_a, out);
}

// Round 10
// 17.122 us; speedup vs baseline: 1.0149x; 1.0149x over previous
//
#include <hip/hip_runtime.h>
#include <hip/hip_bf16.h>

#define Mdim 50
#define Ndim 10000
#define Edim 128
#define NT 200                  // row tiles of 16 (3200/16)
#define XSTR 296                // XL stride in shorts (16B-aligned frags, spread banks)
#define HSTR 264                // HF stride in shorts

using s8v   = __attribute__((ext_vector_type(8))) short;
using f32x4 = __attribute__((ext_vector_type(4))) float;

__device__ __forceinline__ short f2bf(float x) {
    return __builtin_bit_cast(short, __float2bfloat16(x));
}
__device__ __forceinline__ s8v cvt8(float4 a, float4 b) {
    s8v v;
    v[0] = f2bf(a.x); v[1] = f2bf(a.y); v[2] = f2bf(a.z); v[3] = f2bf(a.w);
    v[4] = f2bf(b.x); v[5] = f2bf(b.y); v[6] = f2bf(b.z); v[7] = f2bf(b.w);
    return v;
}
__device__ __forceinline__ s8v ld8g(const float* __restrict__ p) {
    const float4* q = (const float4*)p;
    return cvt8(q[0], q[1]);
}

// Single kernel, 200 blocks x 512 threads (8 waves). Block t: rows 16t..16t+15.
// Wave w owns output n-tile w (channels 16w..16w+15); its 21 B-fragments are
// register-resident, loaded in one early batch (weights are L2-resident).
// Fragment convention: lane l=(r16=l&15, h=l>>4) holds row r16, k-cols kt*32+h*8..+7.
// C/D layout: col = lane&15, row = (lane>>4)*4 + reg.
// out = [gvec | h] @ W_a^T + b_a  (K=256), gvec = graph_row @ W_g^T + b_g,
// h = X @ Wc^T (K=288, bias folded at col 267, X col 267 = 1.0).
__global__ __launch_bounds__(512) void k_one(
    const float* __restrict__ cities, const float* __restrict__ graph,
    const float* __restrict__ astate,
    const float* __restrict__ W_dp, const float* __restrict__ b_dp,
    const float* __restrict__ W_dc, const float* __restrict__ b_dc,
    const float* __restrict__ W_nc, const float* __restrict__ b_nc,
    const float* __restrict__ W_ps, const float* __restrict__ b_ps,
    const float* __restrict__ W_g,  const float* __restrict__ b_g,
    const float* __restrict__ W_a,  const float* __restrict__ b_a,
    float* __restrict__ out)
{
    const int t = blockIdx.x, tid = threadIdx.x;
    const int w = tid >> 6, l = tid & 63;
    const int r16 = l & 15, h = l >> 4;
    const int o = w * 16 + r16;          // B-row / output channel for this lane
    const int kb = h * 8;                // k-offset within a 32-wide K-tile

    __shared__ float AS[16][13];
    __shared__ __align__(16) short GL[2][136];
    __shared__ __align__(16) short XL[16][XSTR];
    __shared__ __align__(16) short HF[16][HSTR];   // cols 0..127 gvec, 128..255 h

    // ---- issue ALL B-fragment loads early (independent, latency-overlapped) ----
    s8v Bc[9], Ba[8], Bg[4];
    {
        const float* wdp = W_dp + (size_t)o * 256;
        #pragma unroll
        for (int kt = 0; kt < 8; ++kt) Bc[kt] = ld8g(wdp + kt * 32 + kb);
        s8v bf = (s8v)0;                 // kt=8: cols 256..287 = dc(4)|nc(4)|ps(3)|bias
        if (h == 0) {
            bf = cvt8(*(const float4*)(W_dc + o * 4), *(const float4*)(W_nc + o * 4));
        } else if (h == 1) {
            bf[0] = f2bf(W_ps[o * 3]); bf[1] = f2bf(W_ps[o * 3 + 1]); bf[2] = f2bf(W_ps[o * 3 + 2]);
            bf[3] = f2bf(b_dp[o] + b_dc[o] + b_nc[o] + b_ps[o]);
        }
        Bc[8] = bf;
        const float* wa = W_a + (size_t)o * 256;
        #pragma unroll
        for (int kt = 0; kt < 8; ++kt) Ba[kt] = ld8g(wa + kt * 32 + kb);
        const float* wg = W_g + (size_t)o * Edim;
        #pragma unroll
        for (int kt = 0; kt < 4; ++kt) Bg[kt] = ld8g(wg + kt * 32 + kb);
    }
    const float bgv = b_g[o], bav = b_a[o];

    // ---- stage agent rows + graph rows ----
    const int blo = (t * 16) / Mdim;
    if (tid < 16 * 13) AS[tid / 13][tid % 13] = astate[t * 16 * 13 + tid];
    if (tid < 256) {
        const int row = tid >> 7, c = tid & 127;
        const int bb = min(blo + row, 63);
        GL[row][c] = f2bf(graph[bb * Edim + c]);
    }
    __syncthreads();

    // ---- gather 32 city rows coalesced into XL (512 thr x 2 float4) ----
    #pragma unroll
    for (int i = 0; i < 2; ++i) {
        const int f = (i * 512 + tid) * 4;     // 0..4092, step 4
        const int r = f >> 8, c = f & 255;
        const int b = (t * 16 + r) / Mdim;
        int ci = (int)AS[r][c < 128 ? 0 : 1];
        ci = min(max(ci, 0), Ndim - 1);
        const float4 v = *(const float4*)(cities + ((size_t)b * Ndim + ci) * Edim + (c & 127));
        XL[r][c]     = f2bf(v.x);
        XL[r][c + 1] = f2bf(v.y);
        XL[r][c + 2] = f2bf(v.z);
        XL[r][c + 3] = f2bf(v.w);
    }
    {   // feats cols 256..287: 512 threads = 16 rows x 32 cols, one each
        const int r = tid >> 5, cc = tid & 31;
        float x = 0.f;
        if (cc < 11)       x = AS[r][2 + cc];
        else if (cc == 11) x = 1.0f;
        XL[r][256 + cc] = f2bf(x);
    }

    // ---- GEMM_g (overlaps gather): gvec -> HF[:, 0:128] ----
    const int selr = (t * 16 + r16) / Mdim - blo;      // 0/1: lane-row's graph row
    f32x4 ag = (f32x4)0.f;
    #pragma unroll
    for (int kt = 0; kt < 4; ++kt) {
        const s8v A = *(const s8v*)&GL[selr][kt * 32 + kb];
        ag = __builtin_amdgcn_mfma_f32_16x16x32_bf16(A, Bg[kt], ag, 0, 0, 0);
    }
    #pragma unroll
    for (int r = 0; r < 4; ++r) HF[h * 4 + r][o] = f2bf(ag[r] + bgv);
    __syncthreads();

    // ---- GEMM1: h = X @ Wc^T -> HF[:, 128:256] ----
    f32x4 a1 = (f32x4)0.f;
    #pragma unroll
    for (int kt = 0; kt < 9; ++kt) {
        const s8v A = *(const s8v*)&XL[r16][kt * 32 + kb];
        a1 = __builtin_amdgcn_mfma_f32_16x16x32_bf16(A, Bc[kt], a1, 0, 0, 0);
    }
    #pragma unroll
    for (int r = 0; r < 4; ++r) HF[h * 4 + r][Edim + o] = f2bf(a1[r]);
    __syncthreads();

    // ---- GEMM2: out = [gvec|h] @ W_a^T + b_a (K=256) ----
    f32x4 a2 = (f32x4)0.f;
    #pragma unroll
    for (int kt = 0; kt < 8; ++kt) {
        const s8v A = *(const s8v*)&HF[r16][kt * 32 + kb];
        a2 = __builtin_amdgcn_mfma_f32_16x16x32_bf16(A, Ba[kt], a2, 0, 0, 0);
    }
    #pragma unroll
    for (int r = 0; r < 4; ++r) {
        const int R2 = t * 16 + h * 4 + r;
        out[(size_t)R2 * Edim + o] = a2[r] + bav;
    }
}

extern "C" void kernel_launch(void* const* d_in, const int* in_sizes, int n_in,
                              void* d_out, int out_size, void* d_ws, size_t ws_size,
                              hipStream_t stream) {
    const float* cities = (const float*)d_in[0];
    const float* graph  = (const float*)d_in[1];
    const float* astate = (const float*)d_in[2];
    const float* W_dp = (const float*)d_in[3];
    const float* b_dp = (const float*)d_in[4];
    const float* W_dc = (const float*)d_in[5];
    const float* b_dc = (const float*)d_in[6];
    const float* W_nc = (const float*)d_in[7];
    const float* b_nc = (const float*)d_in[8];
    const float* W_ps = (const float*)d_in[9];
    const float* b_ps = (const float*)d_in[10];
    const float* W_g  = (const float*)d_in[11];
    const float* b_g  = (const float*)d_in[12];
    const float* W_a  = (const float*)d_in[13];
    const float* b_a  = (const float*)d_in[14];
    float* out = (float*)d_out;

    hipLaunchKernelGGL(k_one, dim3(NT), dim3(512), 0, stream,
                       cities, graph, astate,
                       W_dp, b_dp, W_dc, b_dc, W_nc, b_nc, W_ps, b_ps,
                       W_g, b_g, W_a, b_a, out);
}